// Round 7
// baseline (235.856 us; speedup 1.0000x reference)
//
#include <hip/hip_runtime.h>
#include <math.h>

#define CDIM 256
#define CKD  32
#define NPIX 4096
#define BATCH 4
#define NMACRO (NPIX / 64)

typedef __attribute__((ext_vector_type(8)))  short bf16x8;
typedef __attribute__((ext_vector_type(16))) float f32x16;

#if __has_builtin(__builtin_amdgcn_exp2f)
#define EXP2(x) __builtin_amdgcn_exp2f(x)
#else
#define EXP2(x) exp2f(x)
#endif

__device__ inline ushort f2bf(float x) {
    unsigned u = __float_as_uint(x);
    u += 0x7fffu + ((u >> 16) & 1u);   // round-to-nearest-even
    return (ushort)(u >> 16);
}
__device__ inline unsigned packbf(float a, float b) {
    return (unsigned)f2bf(a) | ((unsigned)f2bf(b) << 16);
}
// packed f32x2 -> bf16x2, RNE (identical rounding to f2bf), 1 instr
__device__ inline unsigned cvtpk(float a, float b) {
    unsigned r;
    asm("v_cvt_pk_bf16_f32 %0, %1, %2" : "=v"(r) : "v"(a), "v"(b));
    return r;
}
// a,b: swap a's high 32 lanes with b's low 32 lanes (v_permlane32_swap_b32)
__device__ inline void lane32swap(unsigned &a, unsigned &b) {
    asm("v_permlane32_swap_b32 %0, %1" : "+v"(a), "+v"(b));
}

#define LDS_ASYNC16(gptr, lptr) \
  __builtin_amdgcn_global_load_lds((const __attribute__((address_space(1))) void*)(gptr), \
                                   (__attribute__((address_space(3))) void*)(lptr), 16, 0, 0)

// ---------------- Kernel 0: prep Wt[320][256] bf16 = [Wh^T; Wf^T; Wg^T] ----
__global__ __launch_bounds__(256) void prep_kernel(
    const float* __restrict__ Wh, const float* __restrict__ Wf,
    const float* __restrict__ Wg, ushort* __restrict__ Wt)
{
    __shared__ float ls[64 * 65];
    const int tid = threadIdx.x;
    const int bid = blockIdx.x;

    if (bid < 16) {                 // Wh 64x64 tile transpose
        const int k0 = (bid & 3) * 64, c0 = (bid >> 2) * 64;
        #pragma unroll
        for (int i = 0; i < 16; ++i) {
            int r = i * 4 + (tid >> 6), c = tid & 63;
            ls[r * 65 + c] = Wh[(k0 + r) * 256 + c0 + c];
        }
        __syncthreads();
        #pragma unroll
        for (int i = 0; i < 16; ++i) {
            int cr = i * 4 + (tid >> 6), k = tid & 63;
            Wt[(c0 + cr) * 256 + k0 + k] = f2bf(ls[k * 65 + cr]);
        }
    } else {                        // Wf/Wg [256k x 32c] -> Wt rows 256+
        const float* W = (bid == 16) ? Wf : Wg;
        const int rbase = 256 + (bid - 16) * 32;
        #pragma unroll
        for (int kh2 = 0; kh2 < 2; ++kh2) {
            __syncthreads();
            #pragma unroll
            for (int i = 0; i < 16; ++i) {
                int flat = i * 256 + tid;
                int k = flat >> 5, c = flat & 31;
                ls[c * 129 + k] = W[(kh2 * 128 + k) * 32 + c];
            }
            __syncthreads();
            #pragma unroll
            for (int i = 0; i < 16; ++i) {
                int flat = i * 256 + tid;
                int c = flat >> 7, k = flat & 127;
                Wt[(rbase + c) * 256 + kh2 * 128 + k] = f2bf(ls[c * 129 + k]);
            }
        }
    }
}

// ---------------- Kernel 1: MFMA projections (32 px/block, R3 version) ----
// 512 blocks (2/CU), 4 waves, 32 px each. K=256, 8 slabs of 32, dbuf LDS.
// g/glo outputs are pre-scaled by log2(e) so attn uses bare exp2.
// R6's 64px variant was ~4-6us SLOWER (1 block/CU lost overlap) - reverted.
__global__ __launch_bounds__(256) void proj_kernel(
    const float*  __restrict__ x,    // [B*N, 256] fp32
    const ushort* __restrict__ Wt,   // [320, 256] bf16
    const float*  __restrict__ bfp, const float* __restrict__ bgp,
    const float*  __restrict__ bhp,
    ushort* __restrict__ fo,         // bf16 [B*N, 32]
    ushort* __restrict__ go,         // bf16 [B*N, 32]
    ushort* __restrict__ glo,        // bf16 [B*N, 32]  g residual
    ushort* __restrict__ ht)         // bf16 [B*64][256][64] tiled values^T
{
    __shared__ ushort wls[2][1280 * 8];
    __shared__ ushort xls[2][128 * 8];

    const int tid  = threadIdx.x;
    const int w    = tid >> 6;
    const int lane = tid & 63;
    const int hl   = lane >> 5;
    const int ln   = lane & 31;
    const int bid  = blockIdx.x;
    const long long px0 = (long long)bid * 32;
    const int b    = (int)(px0 >> 12);
    const int n0   = (int)(px0 & (NPIX - 1));
    const int kt   = n0 >> 6;
    const int koff = n0 & 63;

    const int sx_px = tid >> 3, sx_j = tid & 7;
    const int sx_o = sx_j >> 1, sx_h = sx_j & 1;
    const int sx_slot = sx_o * 32 + ((sx_px + 2 * sx_o) & 31);

    #pragma unroll
    for (int i = 0; i < 5; ++i) {
        int s = i * 256 + tid;
        int n = s >> 2, o = ((s & 3) - (n >> 1)) & 3;
        LDS_ASYNC16(Wt + n * 256 + o * 8, &wls[0][s * 8]);
    }
    {
        float4 v = *(const float4*)(x + (px0 + sx_px) * CDIM + sx_j * 4);
        uint2 p; p.x = packbf(v.x, v.y); p.y = packbf(v.z, v.w);
        *(uint2*)&xls[0][sx_slot * 8 + sx_h * 4] = p;
    }

    f32x16 acc0={0,0,0,0,0,0,0,0,0,0,0,0,0,0,0,0};
    f32x16 acc1={0,0,0,0,0,0,0,0,0,0,0,0,0,0,0,0};
    f32x16 accfg={0,0,0,0,0,0,0,0,0,0,0,0,0,0,0,0};

    for (int sl = 0; sl < 8; ++sl) {
        const int cur = sl & 1;
        __syncthreads();
        if (sl + 1 < 8) {
            const int nxt = cur ^ 1;
            #pragma unroll
            for (int i = 0; i < 5; ++i) {
                int s = i * 256 + tid;
                int n = s >> 2, o = ((s & 3) - (n >> 1)) & 3;
                LDS_ASYNC16(Wt + n * 256 + (sl + 1) * 32 + o * 8, &wls[nxt][s * 8]);
            }
            float4 v = *(const float4*)(x + (px0 + sx_px) * CDIM + (sl + 1) * 32 + sx_j * 4);
            uint2 p; p.x = packbf(v.x, v.y); p.y = packbf(v.z, v.w);
            *(uint2*)&xls[nxt][sx_slot * 8 + sx_h * 4] = p;
        }

        #pragma unroll
        for (int st = 0; st < 2; ++st) {
            const int o = st * 2 + hl;
            #define LDW(n) (*(const bf16x8*)&wls[cur][((n) * 4 + (((o) + ((n) >> 1)) & 3)) * 8])
            bf16x8 xb  = *(const bf16x8*)&xls[cur][(o * 32 + ((ln + 2 * o) & 31)) * 8];
            bf16x8 wa0 = LDW(w * 64 + ln);
            bf16x8 wa1 = LDW(w * 64 + 32 + ln);
            acc0 = __builtin_amdgcn_mfma_f32_32x32x16_bf16(wa0, xb, acc0, 0, 0, 0);
            acc1 = __builtin_amdgcn_mfma_f32_32x32x16_bf16(wa1, xb, acc1, 0, 0, 0);
            if (w < 2) {
                bf16x8 wfg = LDW(256 + w * 32 + ln);
                accfg = __builtin_amdgcn_mfma_f32_32x32x16_bf16(xb, wfg, accfg, 0, 0, 0);
            }
            #undef LDW
        }
    }

    ushort* htt = ht + ((long long)(b * 64 + kt) * CDIM) * 64 + koff;
    #pragma unroll
    for (int r = 0; r < 16; ++r) {
        const int rowD = (r & 3) + 8 * (r >> 2) + 4 * hl;
        int c0 = w * 64 + rowD, c1 = c0 + 32;
        htt[(long long)c0 * 64 + ln] = f2bf(acc0[r] + bhp[c0]);
        htt[(long long)c1 * 64 + ln] = f2bf(acc1[r] + bhp[c1]);
    }
    if (w < 2) {
        const float bb = (w ? bgp : bfp)[ln];
        const float scl = w ? 1.44269504088896f : 1.0f;  // fold log2(e) into g
        #pragma unroll
        for (int r = 0; r < 16; ++r) {
            const int rowD = (r & 3) + 8 * (r >> 2) + 4 * hl;
            float v = (accfg[r] + bb) * scl;
            ushort hi = f2bf(v);
            long long idx = (px0 + rowD) * CKD + ln;
            if (w == 0) {
                fo[idx] = hi;
            } else {
                go[idx] = hi;
                float hif = __uint_as_float(((unsigned)hi) << 16);
                glo[idx] = f2bf(v - hif);
            }
        }
    }
}

// ---------------- Kernel 2: MFMA attention, NO-LDS barrier-free loop ------
// Block = 128 q x 128 ch, 4 waves (wave w owns q-band w*32..+31), kh inner.
// R6 analysis: ~2100 cyc/macro of the 7240-cyc slot was barrier-convoy +
// LDS-pipe stall; the staged hh tile (16 KB, L1-resident) is fully re-read
// by every wave anyway. So f and hv MFMA fragments are read DIRECTLY from
// global at the exact pre-swizzle addresses the LDS staging used (layout
// UNCHANGED in proj; slot<->address algebra verified both directions):
//   fb0  = fk[b] + (kt*64 + kh*32 + ln)*32 + hl*8        (+16 for fb1)
//   hb_i = hv[b] + kt*16384 + (chs*128 + i*32 + ln)*64 + (kh*4+ck*2+hl)*8
// The macro loop has ZERO barriers / ZERO LDS: 12 independent waves per CU,
// loads freely hoistable across macros by the compiler. One __syncthreads
// remains (l_red epilogue exchange).
__global__ __launch_bounds__(256, 3) void attn_kernel(
    const float*  __restrict__ x,
    const ushort* __restrict__ fk,   // bf16 [B*N,32] keys
    const ushort* __restrict__ gq,   // bf16 [B*N,32] queries (hi, *log2e)
    const ushort* __restrict__ glo,  // bf16 [B*N,32] queries (lo residual)
    const ushort* __restrict__ hv,   // bf16 tiled [B*64][256][64] values^T
    float* __restrict__ out,
    float* __restrict__ Opart,       // [nks][B][N][256] f32 (or null)
    float* __restrict__ Lpart,       // [nks][B][N] f32 (or null)
    int nks)
{
    __shared__ float l_red[128];

    const int tid  = threadIdx.x;
    const int w    = tid >> 6;           // q-band 0..3
    const int lane = tid & 63;
    const int hl   = lane >> 5;
    const int ln   = lane & 31;

    const int bid = blockIdx.x;
    const int chs = bid & 1;
    const int b   = (bid >> 1) & 3;
    const int qt  = (bid >> 3) & 31;     // 0..31
    const int ks  = bid >> 8;            // 0..nks-1
    const int q0  = qt * 128;
    const int kt0 = (ks * NMACRO) / nks;
    const int kt1 = ((ks + 1) * NMACRO) / nks;

    const long long bbase = (long long)b * NPIX;
    const ushort* fbase = fk + bbase * CKD;
    const ushort* htb   = hv + (long long)b * 64 * (CDIM * 64);
    // per-lane fragment bases (macro-invariant parts)
    const ushort* fpl = fbase + (long long)(hl * 8);            // + (kt*64+kh*32+ln)*32
    const ushort* hpl = htb + (long long)(chs * 128 + ln) * 64; // + kt*16384 + i*2048 + oct*8

    const ushort* gp  = gq  + (bbase + q0 + w * 32 + ln) * CKD;
    const ushort* glp = glo + (bbase + q0 + w * 32 + ln) * CKD;
    const bf16x8 ga0 = *(const bf16x8*)(gp + hl * 8);
    const bf16x8 ga1 = *(const bf16x8*)(gp + 16 + hl * 8);
    const bf16x8 gl0 = *(const bf16x8*)(glp + hl * 8);
    const bf16x8 gl1 = *(const bf16x8*)(glp + 16 + hl * 8);

    const f32x16 Zv = {0,0,0,0,0,0,0,0,0,0,0,0,0,0,0,0};
    f32x16 acc0={0,0,0,0,0,0,0,0,0,0,0,0,0,0,0,0};
    f32x16 acc1={0,0,0,0,0,0,0,0,0,0,0,0,0,0,0,0};
    f32x16 acc2={0,0,0,0,0,0,0,0,0,0,0,0,0,0,0,0};
    f32x16 acc3={0,0,0,0,0,0,0,0,0,0,0,0,0,0,0,0};
    float lsA = 0.f, lsB = 0.f;

    #pragma unroll 2
    for (int kt = kt0; kt < kt1; ++kt) {
        const ushort* hmac = hpl + (long long)kt * 16384;

        #pragma unroll
        for (int kh = 0; kh < 2; ++kh) {
            // f fragments for this 32-key strip (direct, 16B/lane)
            const ushort* fK = fpl + (long long)(kt * 64 + kh * 32 + ln) * CKD;
            bf16x8 fb0 = *(const bf16x8*)(fK);
            bf16x8 fb1 = *(const bf16x8*)(fK + 16);

            // QK: S^T(32k x 32q) = f(A) . g(B); hi/lo as two parallel
            // 2-chains merged at the exp2 argument
            f32x16 S, T;
            __builtin_amdgcn_s_setprio(1);
            S = __builtin_amdgcn_mfma_f32_32x32x16_bf16(fb0, ga0, Zv, 0, 0, 0);
            T = __builtin_amdgcn_mfma_f32_32x32x16_bf16(fb0, gl0, Zv, 0, 0, 0);
            S = __builtin_amdgcn_mfma_f32_32x32x16_bf16(fb1, ga1, S, 0, 0, 0);
            T = __builtin_amdgcn_mfma_f32_32x32x16_bf16(fb1, gl1, T, 0, 0, 0);
            __builtin_amdgcn_s_setprio(0);

            // p = exp2(s_hi + s_lo) in regs (|s|*log2e << 127, no clamp)
            float p[16];
            #pragma unroll
            for (int r = 0; r < 16; ++r) {
                p[r] = EXP2(S[r] + T[r]);
                if (r & 1) lsB += p[r]; else lsA += p[r];
            }
            unsigned U[8];
            #pragma unroll
            for (int m2 = 0; m2 < 8; ++m2) U[m2] = cvtpk(p[2*m2], p[2*m2+1]);

            // PV over this 32-key strip: A-frags via permlane32_swap,
            // B-frags (values) direct from global (L1-resident tile)
            const ushort* hK = hmac + (kh * 4 + hl) * 8;
            #pragma unroll
            for (int ck = 0; ck < 2; ++ck) {
                unsigned a0 = U[4*ck + 0], a1 = U[4*ck + 1];
                unsigned a2 = U[4*ck + 2], a3 = U[4*ck + 3];
                lane32swap(a0, a2);   // a0 = pf[0], a2 = pf[2]
                lane32swap(a1, a3);   // a1 = pf[1], a3 = pf[3]
                union { unsigned i[4]; bf16x8 v; } pf;
                pf.i[0] = a0; pf.i[1] = a1; pf.i[2] = a2; pf.i[3] = a3;
                bf16x8 pa = pf.v;
                bf16x8 hb0 = *(const bf16x8*)(hK + ck * 16);
                bf16x8 hb1 = *(const bf16x8*)(hK + ck * 16 + 2048);
                bf16x8 hb2 = *(const bf16x8*)(hK + ck * 16 + 4096);
                bf16x8 hb3 = *(const bf16x8*)(hK + ck * 16 + 6144);
                __builtin_amdgcn_s_setprio(1);
                acc0 = __builtin_amdgcn_mfma_f32_32x32x16_bf16(pa, hb0, acc0, 0, 0, 0);
                acc1 = __builtin_amdgcn_mfma_f32_32x32x16_bf16(pa, hb1, acc1, 0, 0, 0);
                acc2 = __builtin_amdgcn_mfma_f32_32x32x16_bf16(pa, hb2, acc2, 0, 0, 0);
                acc3 = __builtin_amdgcn_mfma_f32_32x32x16_bf16(pa, hb3, acc3, 0, 0, 0);
                __builtin_amdgcn_s_setprio(0);
            }
        }
    }

    // ---- l broadcast: lane holds l(query=ln); acc rows are query=rowD,
    // so bounce l through LDS and read back with the row index (broadcast).
    float lsum = lsA + lsB;
    lsum += __shfl_xor(lsum, 32);
    if (hl == 0) l_red[w * 32 + ln] = lsum;
    __syncthreads();

    if (Opart) {
        // ---- partial epilogue: raw O sums + l to workspace
        const long long pb = ((long long)(ks * BATCH + b) * NPIX + q0);
        if (chs == 0 && hl == 0) Lpart[pb + w * 32 + ln] = lsum;
        #pragma unroll
        for (int r = 0; r < 16; ++r) {
            int rowD = (r & 3) + 8 * (r >> 2) + 4 * hl;
            int ql = w * 32 + rowD;
            long long rg = (pb + ql) * CDIM + chs * 128 + ln;
            Opart[rg]      = acc0[r];
            Opart[rg + 32] = acc1[r];
            Opart[rg + 64] = acc2[r];
            Opart[rg + 96] = acc3[r];
        }
    } else {
        // ---- direct epilogue: out = x + O/l
        #pragma unroll
        for (int r = 0; r < 16; ++r) {
            int rowD = (r & 3) + 8 * (r >> 2) + 4 * hl;
            int ql = w * 32 + rowD;
            float linv = 1.f / l_red[ql];
            long long rg = (bbase + q0 + ql) * CDIM + chs * 128 + ln;
            out[rg]      = x[rg]      + acc0[r] * linv;
            out[rg + 32] = x[rg + 32] + acc1[r] * linv;
            out[rg + 64] = x[rg + 64] + acc2[r] * linv;
            out[rg + 96] = x[rg + 96] + acc3[r] * linv;
        }
    }
}

// ---------------- Kernel 3: combine partials ------------------------------
// out[b,q,:] = x[b,q,:] + (sum_ks O[ks,b,q,:]) / (sum_ks l[ks,b,q]).
// 4096 blocks x 4 waves; one 256-ch row per wave (64 lanes x float4).
__global__ __launch_bounds__(256) void combine_kernel(
    const float* __restrict__ x, const float* __restrict__ Op,
    const float* __restrict__ Lp, float* __restrict__ out, int nks)
{
    const int tid = threadIdx.x, w = tid >> 6, lane = tid & 63;
    const int row = blockIdx.x * 4 + w;          // [0, B*N)
    const int b = row >> 12, q = row & (NPIX - 1);

    float l = 0.f;
    for (int ks = 0; ks < nks; ++ks)
        l += Lp[(ks * BATCH + b) * NPIX + q];
    const float linv = 1.f / l;

    float4 a = {0.f, 0.f, 0.f, 0.f};
    for (int ks = 0; ks < nks; ++ks) {
        const float4 v = *(const float4*)&Op[
            (((long long)(ks * BATCH + b) * NPIX + q)) * CDIM + lane * 4];
        a.x += v.x; a.y += v.y; a.z += v.z; a.w += v.w;
    }
    const long long g = ((long long)b * NPIX + q) * CDIM + lane * 4;
    const float4 xv = *(const float4*)&x[g];
    float4 o;
    o.x = xv.x + a.x * linv;
    o.y = xv.y + a.y * linv;
    o.z = xv.z + a.z * linv;
    o.w = xv.w + a.w * linv;
    *(float4*)&out[g] = o;
}

extern "C" void kernel_launch(void* const* d_in, const int* in_sizes, int n_in,
                              void* d_out, int out_size, void* d_ws, size_t ws_size,
                              hipStream_t stream) {
    const float* x  = (const float*)d_in[0];
    const float* Wf = (const float*)d_in[1];
    const float* bf = (const float*)d_in[2];
    const float* Wg = (const float*)d_in[3];
    const float* bg = (const float*)d_in[4];
    const float* Wh = (const float*)d_in[5];
    const float* bh = (const float*)d_in[6];
    float* out = (float*)d_out;

    ushort* fbf = (ushort*)d_ws;                 // bf16 keys      [B*N,32]
    ushort* gbf = fbf + BATCH * NPIX * CKD;      // bf16 queries   [B*N,32]
    ushort* glo = gbf + BATCH * NPIX * CKD;      // bf16 q-residual[B*N,32]
    ushort* ht  = glo + BATCH * NPIX * CKD;      // bf16 tiled values^T
    ushort* Wt  = ht + BATCH * NPIX * CDIM;      // bf16 [320,256]
    char*   pb  = (char*)(Wt + 320 * 256);       // end of base usage

    const int NKS = 3;
    const size_t base_used = (size_t)(pb - (char*)d_ws);
    const size_t oelems = (size_t)NKS * BATCH * NPIX * CDIM;
    const size_t lelems = (size_t)NKS * BATCH * NPIX;
    float* Opart = nullptr;
    float* Lpart = nullptr;
    int nks = 1;
    if (ws_size >= base_used + (oelems + lelems) * sizeof(float)) {
        nks = NKS;
        Opart = (float*)pb;
        Lpart = Opart + oelems;
    }

    prep_kernel<<<dim3(18), 256, 0, stream>>>(Wh, Wf, Wg, Wt);
    proj_kernel<<<dim3(512), 256, 0, stream>>>(x, Wt, bf, bg, bh, fbf, gbf, glo, ht);
    attn_kernel<<<dim3(256 * nks), 256, 0, stream>>>(x, fbf, gbf, glo, ht, out,
                                                     Opart, Lpart, nks);
    if (nks > 1)
        combine_kernel<<<dim3(BATCH * NPIX / 4), 256, 0, stream>>>(x, Opart, Lpart, out, nks);
}

// Round 9
// 154.242 us; speedup vs baseline: 1.5291x; 1.5291x over previous
//
#include <hip/hip_runtime.h>
#include <math.h>

#define CDIM 256
#define CKD  32
#define NPIX 4096
#define BATCH 4
#define NMACRO (NPIX / 64)

typedef __attribute__((ext_vector_type(8)))  short bf16x8;
typedef __attribute__((ext_vector_type(16))) float f32x16;

#if __has_builtin(__builtin_amdgcn_exp2f)
#define EXP2(x) __builtin_amdgcn_exp2f(x)
#else
#define EXP2(x) exp2f(x)
#endif

__device__ inline ushort f2bf(float x) {
    unsigned u = __float_as_uint(x);
    u += 0x7fffu + ((u >> 16) & 1u);   // round-to-nearest-even
    return (ushort)(u >> 16);
}
__device__ inline unsigned packbf(float a, float b) {
    return (unsigned)f2bf(a) | ((unsigned)f2bf(b) << 16);
}
// packed f32x2 -> bf16x2, RNE (identical rounding to f2bf), 1 instr
__device__ inline unsigned cvtpk(float a, float b) {
    unsigned r;
    asm("v_cvt_pk_bf16_f32 %0, %1, %2" : "=v"(r) : "v"(a), "v"(b));
    return r;
}
// a,b: swap a's high 32 lanes with b's low 32 lanes (v_permlane32_swap_b32)
__device__ inline void lane32swap(unsigned &a, unsigned &b) {
    asm("v_permlane32_swap_b32 %0, %1" : "+v"(a), "+v"(b));
}

#define LDS_ASYNC16(gptr, lptr) \
  __builtin_amdgcn_global_load_lds((const __attribute__((address_space(1))) void*)(gptr), \
                                   (__attribute__((address_space(3))) void*)(lptr), 16, 0, 0)

// ---------------- Kernel 0: prep Wt[320][256] bf16 = [Wh^T; Wf^T; Wg^T] ----
__global__ __launch_bounds__(256) void prep_kernel(
    const float* __restrict__ Wh, const float* __restrict__ Wf,
    const float* __restrict__ Wg, ushort* __restrict__ Wt)
{
    __shared__ float ls[64 * 65];
    const int tid = threadIdx.x;
    const int bid = blockIdx.x;

    if (bid < 16) {                 // Wh 64x64 tile transpose
        const int k0 = (bid & 3) * 64, c0 = (bid >> 2) * 64;
        #pragma unroll
        for (int i = 0; i < 16; ++i) {
            int r = i * 4 + (tid >> 6), c = tid & 63;
            ls[r * 65 + c] = Wh[(k0 + r) * 256 + c0 + c];
        }
        __syncthreads();
        #pragma unroll
        for (int i = 0; i < 16; ++i) {
            int cr = i * 4 + (tid >> 6), k = tid & 63;
            Wt[(c0 + cr) * 256 + k0 + k] = f2bf(ls[k * 65 + cr]);
        }
    } else {                        // Wf/Wg [256k x 32c] -> Wt rows 256+
        const float* W = (bid == 16) ? Wf : Wg;
        const int rbase = 256 + (bid - 16) * 32;
        #pragma unroll
        for (int kh2 = 0; kh2 < 2; ++kh2) {
            __syncthreads();
            #pragma unroll
            for (int i = 0; i < 16; ++i) {
                int flat = i * 256 + tid;
                int k = flat >> 5, c = flat & 31;
                ls[c * 129 + k] = W[(kh2 * 128 + k) * 32 + c];
            }
            __syncthreads();
            #pragma unroll
            for (int i = 0; i < 16; ++i) {
                int flat = i * 256 + tid;
                int c = flat >> 7, k = flat & 127;
                Wt[(rbase + c) * 256 + kh2 * 128 + k] = f2bf(ls[c * 129 + k]);
            }
        }
    }
}

// ---------------- Kernel 1: MFMA projections (32 px/block) ----------------
// 512 blocks (2/CU), 4 waves, 32 px each. K=256, 8 slabs of 32, dbuf LDS.
// g/glo outputs are pre-scaled by log2(e) so attn uses bare exp2.
__global__ __launch_bounds__(256) void proj_kernel(
    const float*  __restrict__ x,    // [B*N, 256] fp32
    const ushort* __restrict__ Wt,   // [320, 256] bf16
    const float*  __restrict__ bfp, const float* __restrict__ bgp,
    const float*  __restrict__ bhp,
    ushort* __restrict__ fo,         // bf16 [B*N, 32]
    ushort* __restrict__ go,         // bf16 [B*N, 32]
    ushort* __restrict__ glo,        // bf16 [B*N, 32]  g residual
    ushort* __restrict__ ht)         // bf16 [B*64][256][64] tiled values^T
{
    __shared__ ushort wls[2][1280 * 8];
    __shared__ ushort xls[2][128 * 8];

    const int tid  = threadIdx.x;
    const int w    = tid >> 6;
    const int lane = tid & 63;
    const int hl   = lane >> 5;
    const int ln   = lane & 31;
    const int bid  = blockIdx.x;
    const long long px0 = (long long)bid * 32;
    const int b    = (int)(px0 >> 12);
    const int n0   = (int)(px0 & (NPIX - 1));
    const int kt   = n0 >> 6;
    const int koff = n0 & 63;

    const int sx_px = tid >> 3, sx_j = tid & 7;
    const int sx_o = sx_j >> 1, sx_h = sx_j & 1;
    const int sx_slot = sx_o * 32 + ((sx_px + 2 * sx_o) & 31);

    #pragma unroll
    for (int i = 0; i < 5; ++i) {
        int s = i * 256 + tid;
        int n = s >> 2, o = ((s & 3) - (n >> 1)) & 3;
        LDS_ASYNC16(Wt + n * 256 + o * 8, &wls[0][s * 8]);
    }
    {
        float4 v = *(const float4*)(x + (px0 + sx_px) * CDIM + sx_j * 4);
        uint2 p; p.x = packbf(v.x, v.y); p.y = packbf(v.z, v.w);
        *(uint2*)&xls[0][sx_slot * 8 + sx_h * 4] = p;
    }

    f32x16 acc0={0,0,0,0,0,0,0,0,0,0,0,0,0,0,0,0};
    f32x16 acc1={0,0,0,0,0,0,0,0,0,0,0,0,0,0,0,0};
    f32x16 accfg={0,0,0,0,0,0,0,0,0,0,0,0,0,0,0,0};

    for (int sl = 0; sl < 8; ++sl) {
        const int cur = sl & 1;
        __syncthreads();
        if (sl + 1 < 8) {
            const int nxt = cur ^ 1;
            #pragma unroll
            for (int i = 0; i < 5; ++i) {
                int s = i * 256 + tid;
                int n = s >> 2, o = ((s & 3) - (n >> 1)) & 3;
                LDS_ASYNC16(Wt + n * 256 + (sl + 1) * 32 + o * 8, &wls[nxt][s * 8]);
            }
            float4 v = *(const float4*)(x + (px0 + sx_px) * CDIM + (sl + 1) * 32 + sx_j * 4);
            uint2 p; p.x = packbf(v.x, v.y); p.y = packbf(v.z, v.w);
            *(uint2*)&xls[nxt][sx_slot * 8 + sx_h * 4] = p;
        }

        #pragma unroll
        for (int st = 0; st < 2; ++st) {
            const int o = st * 2 + hl;
            #define LDW(n) (*(const bf16x8*)&wls[cur][((n) * 4 + (((o) + ((n) >> 1)) & 3)) * 8])
            bf16x8 xb  = *(const bf16x8*)&xls[cur][(o * 32 + ((ln + 2 * o) & 31)) * 8];
            bf16x8 wa0 = LDW(w * 64 + ln);
            bf16x8 wa1 = LDW(w * 64 + 32 + ln);
            acc0 = __builtin_amdgcn_mfma_f32_32x32x16_bf16(wa0, xb, acc0, 0, 0, 0);
            acc1 = __builtin_amdgcn_mfma_f32_32x32x16_bf16(wa1, xb, acc1, 0, 0, 0);
            if (w < 2) {
                bf16x8 wfg = LDW(256 + w * 32 + ln);
                accfg = __builtin_amdgcn_mfma_f32_32x32x16_bf16(xb, wfg, accfg, 0, 0, 0);
            }
            #undef LDW
        }
    }

    ushort* htt = ht + ((long long)(b * 64 + kt) * CDIM) * 64 + koff;
    #pragma unroll
    for (int r = 0; r < 16; ++r) {
        const int rowD = (r & 3) + 8 * (r >> 2) + 4 * hl;
        int c0 = w * 64 + rowD, c1 = c0 + 32;
        htt[(long long)c0 * 64 + ln] = f2bf(acc0[r] + bhp[c0]);
        htt[(long long)c1 * 64 + ln] = f2bf(acc1[r] + bhp[c1]);
    }
    if (w < 2) {
        const float bb = (w ? bgp : bfp)[ln];
        const float scl = w ? 1.44269504088896f : 1.0f;  // fold log2(e) into g
        #pragma unroll
        for (int r = 0; r < 16; ++r) {
            const int rowD = (r & 3) + 8 * (r >> 2) + 4 * hl;
            float v = (accfg[r] + bb) * scl;
            ushort hi = f2bf(v);
            long long idx = (px0 + rowD) * CKD + ln;
            if (w == 0) {
                fo[idx] = hi;
            } else {
                go[idx] = hi;
                float hif = __uint_as_float(((unsigned)hi) << 16);
                glo[idx] = f2bf(v - hif);
            }
        }
    }
}

// ---------------- Kernel 2: MFMA attention, chs-MERGED 128q x 256ch -------
// R7 lesson: hv fragments MUST be fetched coalesced -> keep R3's proven
// global_load_lds staging + [ch][octet-swz] LDS + swizzled reads exactly.
// NEW: the chs channel-split is merged away. One block now covers ALL 256
// channels (8 named accumulators), so QK MFMA and the entire softmax VALU
// (exp/pack/lsum) are computed ONCE instead of twice, and each staged tile
// serves 2x the channel work (barriers + LDS-read amplification per unit
// work drop ~40%). 4 waves (wave = q-band), 2 blocks/CU (72.5 KB LDS),
// grid = 128*nks (nks=4 -> 512 balanced; fallback 3 -> 384).
__global__ __launch_bounds__(256, 2) void attn_kernel(
    const float*  __restrict__ x,
    const ushort* __restrict__ fk,   // bf16 [B*N,32] keys
    const ushort* __restrict__ gq,   // bf16 [B*N,32] queries (hi, *log2e)
    const ushort* __restrict__ glo,  // bf16 [B*N,32] queries (lo residual)
    const ushort* __restrict__ hv,   // bf16 tiled [B*64][256][64] values^T
    float* __restrict__ out,
    float* __restrict__ Opart,       // [nks][B][N][256] f32 (or null)
    float* __restrict__ Lpart,       // [nks][B][N] f32 (or null)
    int nks)
{
    __shared__ ushort hh_lds[2][2048 * 8];  // 32 KB each (full 256 ch)
    __shared__ ushort f_lds[2][256 * 8];    //  4 KB each
    __shared__ float  l_red[128];

    const int tid  = threadIdx.x;
    const int w    = tid >> 6;           // q-band 0..3
    const int lane = tid & 63;
    const int hl   = lane >> 5;
    const int ln   = lane & 31;

    const int bid = blockIdx.x;
    const int qt  = bid & 31;            // 0..31
    const int b   = (bid >> 5) & 3;
    const int ks  = bid >> 7;            // 0..nks-1
    const int q0  = qt * 128;
    const int kt0 = (ks * NMACRO) / nks;
    const int kt1 = ((ks + 1) * NMACRO) / nks;
    const int nmac = kt1 - kt0;

    const long long bbase = (long long)b * NPIX;
    const ushort* fbase = fk + bbase * CKD;
    const ushort* htb   = hv + (long long)b * 64 * (CDIM * 64);

    const ushort* gp  = gq  + (bbase + q0 + w * 32 + ln) * CKD;
    const ushort* glp = glo + (bbase + q0 + w * 32 + ln) * CKD;
    const bf16x8 ga0 = *(const bf16x8*)(gp + hl * 8);
    const bf16x8 ga1 = *(const bf16x8*)(gp + 16 + hl * 8);
    const bf16x8 gl0 = *(const bf16x8*)(glp + hl * 8);
    const bf16x8 gl1 = *(const bf16x8*)(glp + 16 + hl * 8);

    {
        const long long tb = (long long)kt0 * (CDIM * 64);
        #pragma unroll
        for (int i = 0; i < 8; ++i) {
            int s = i * 256 + tid;
            int c = s >> 3, j = ((s & 7) - c) & 7;
            LDS_ASYNC16(htb + tb + (long long)c * 64 + j * 8, &hh_lds[0][s * 8]);
        }
        LDS_ASYNC16(fbase + (long long)(kt0 * 64 + (tid & 63)) * CKD + (tid >> 6) * 8,
                    &f_lds[0][tid * 8]);
    }

    const f32x16 Zv = {0,0,0,0,0,0,0,0,0,0,0,0,0,0,0,0};
    f32x16 acc0={0,0,0,0,0,0,0,0,0,0,0,0,0,0,0,0};
    f32x16 acc1={0,0,0,0,0,0,0,0,0,0,0,0,0,0,0,0};
    f32x16 acc2={0,0,0,0,0,0,0,0,0,0,0,0,0,0,0,0};
    f32x16 acc3={0,0,0,0,0,0,0,0,0,0,0,0,0,0,0,0};
    f32x16 acc4={0,0,0,0,0,0,0,0,0,0,0,0,0,0,0,0};
    f32x16 acc5={0,0,0,0,0,0,0,0,0,0,0,0,0,0,0,0};
    f32x16 acc6={0,0,0,0,0,0,0,0,0,0,0,0,0,0,0,0};
    f32x16 acc7={0,0,0,0,0,0,0,0,0,0,0,0,0,0,0,0};
    float lsA = 0.f, lsB = 0.f;

    #pragma unroll 2
    for (int m = 0; m < nmac; ++m) {
        const int kt = kt0 + m;
        const int cur = m & 1;
        __syncthreads();   // staging(m) drained; prev macro's LDS reads done

        // ---- stage macro kt+1 into other buffer (drains at next barrier)
        if (m + 1 < nmac) {
            const int nxt = cur ^ 1;
            const long long tb = (long long)(kt + 1) * (CDIM * 64);
            #pragma unroll
            for (int i = 0; i < 8; ++i) {
                int s = i * 256 + tid;
                int c = s >> 3, j = ((s & 7) - c) & 7;
                LDS_ASYNC16(htb + tb + (long long)c * 64 + j * 8, &hh_lds[nxt][s * 8]);
            }
            LDS_ASYNC16(fbase + (long long)((kt + 1) * 64 + (tid & 63)) * CKD + (tid >> 6) * 8,
                        &f_lds[nxt][tid * 8]);
        }

        // ---- both 32-key strips of this macro, per wave (q-band w)
        #pragma unroll
        for (int kh = 0; kh < 2; ++kh) {
            // QK: S^T(32k x 32q) = f(A) . g(B); hi/lo as two parallel
            // 2-chains merged at the exp2 argument (computed ONCE now)
            f32x16 S, T;
            {
                bf16x8 fb0 = *(const bf16x8*)&f_lds[cur][((hl)     * 64 + kh * 32 + ln) * 8];
                bf16x8 fb1 = *(const bf16x8*)&f_lds[cur][((2 + hl) * 64 + kh * 32 + ln) * 8];
                __builtin_amdgcn_s_setprio(1);
                S = __builtin_amdgcn_mfma_f32_32x32x16_bf16(fb0, ga0, Zv, 0, 0, 0);
                T = __builtin_amdgcn_mfma_f32_32x32x16_bf16(fb0, gl0, Zv, 0, 0, 0);
                S = __builtin_amdgcn_mfma_f32_32x32x16_bf16(fb1, ga1, S, 0, 0, 0);
                T = __builtin_amdgcn_mfma_f32_32x32x16_bf16(fb1, gl1, T, 0, 0, 0);
                __builtin_amdgcn_s_setprio(0);
            }

            // p = exp2(s_hi + s_lo) in regs (|s|*log2e << 127, no clamp)
            float p[16];
            #pragma unroll
            for (int r = 0; r < 16; ++r) {
                p[r] = EXP2(S[r] + T[r]);
                if (r & 1) lsB += p[r]; else lsA += p[r];
            }
            unsigned U[8];
            #pragma unroll
            for (int m2 = 0; m2 < 8; ++m2) U[m2] = cvtpk(p[2*m2], p[2*m2+1]);

            // PV over this 32-key strip, ALL 256 channels (8 accs)
            #pragma unroll
            for (int ck = 0; ck < 2; ++ck) {
                unsigned a0 = U[4*ck + 0], a1 = U[4*ck + 1];
                unsigned a2 = U[4*ck + 2], a3 = U[4*ck + 3];
                lane32swap(a0, a2);   // a0 = pf[0], a2 = pf[2]
                lane32swap(a1, a3);   // a1 = pf[1], a3 = pf[3]
                union { unsigned i[4]; bf16x8 v; } pf;
                pf.i[0] = a0; pf.i[1] = a1; pf.i[2] = a2; pf.i[3] = a3;
                bf16x8 pa = pf.v;
                const int oct = kh * 4 + ck * 2 + hl;
                // slot for channel c: c*8 + ((oct + c) & 7); c = t*32 + ln,
                // and 32 = 0 (mod 8) so the swizzle term is t-invariant.
                const int base0 = (ln * 8 + ((oct + ln) & 7)) * 8;
                const ushort* hbp = &hh_lds[cur][base0];
                bf16x8 hb0 = *(const bf16x8*)(hbp);
                bf16x8 hb1 = *(const bf16x8*)(hbp + 1 * 2048);
                bf16x8 hb2 = *(const bf16x8*)(hbp + 2 * 2048);
                bf16x8 hb3 = *(const bf16x8*)(hbp + 3 * 2048);
                bf16x8 hb4 = *(const bf16x8*)(hbp + 4 * 2048);
                bf16x8 hb5 = *(const bf16x8*)(hbp + 5 * 2048);
                bf16x8 hb6 = *(const bf16x8*)(hbp + 6 * 2048);
                bf16x8 hb7 = *(const bf16x8*)(hbp + 7 * 2048);
                __builtin_amdgcn_s_setprio(1);
                acc0 = __builtin_amdgcn_mfma_f32_32x32x16_bf16(pa, hb0, acc0, 0, 0, 0);
                acc1 = __builtin_amdgcn_mfma_f32_32x32x16_bf16(pa, hb1, acc1, 0, 0, 0);
                acc2 = __builtin_amdgcn_mfma_f32_32x32x16_bf16(pa, hb2, acc2, 0, 0, 0);
                acc3 = __builtin_amdgcn_mfma_f32_32x32x16_bf16(pa, hb3, acc3, 0, 0, 0);
                acc4 = __builtin_amdgcn_mfma_f32_32x32x16_bf16(pa, hb4, acc4, 0, 0, 0);
                acc5 = __builtin_amdgcn_mfma_f32_32x32x16_bf16(pa, hb5, acc5, 0, 0, 0);
                acc6 = __builtin_amdgcn_mfma_f32_32x32x16_bf16(pa, hb6, acc6, 0, 0, 0);
                acc7 = __builtin_amdgcn_mfma_f32_32x32x16_bf16(pa, hb7, acc7, 0, 0, 0);
                __builtin_amdgcn_s_setprio(0);
            }
        }
    }

    // ---- l broadcast: lane holds l(query=ln); acc rows are query=rowD,
    // so bounce l through LDS and read back with the row index (broadcast).
    float lsum = lsA + lsB;
    lsum += __shfl_xor(lsum, 32);
    if (hl == 0) l_red[w * 32 + ln] = lsum;
    __syncthreads();

    if (Opart) {
        // ---- partial epilogue: raw O sums + l to workspace
        const long long pb = ((long long)(ks * BATCH + b) * NPIX + q0);
        if (hl == 0) Lpart[pb + w * 32 + ln] = lsum;
        #pragma unroll
        for (int r = 0; r < 16; ++r) {
            int rowD = (r & 3) + 8 * (r >> 2) + 4 * hl;
            int ql = w * 32 + rowD;
            long long rg = (pb + ql) * CDIM + ln;
            Opart[rg]       = acc0[r];
            Opart[rg +  32] = acc1[r];
            Opart[rg +  64] = acc2[r];
            Opart[rg +  96] = acc3[r];
            Opart[rg + 128] = acc4[r];
            Opart[rg + 160] = acc5[r];
            Opart[rg + 192] = acc6[r];
            Opart[rg + 224] = acc7[r];
        }
    } else {
        // ---- direct epilogue: out = x + O/l
        #pragma unroll
        for (int r = 0; r < 16; ++r) {
            int rowD = (r & 3) + 8 * (r >> 2) + 4 * hl;
            int ql = w * 32 + rowD;
            float linv = 1.f / l_red[ql];
            long long rg = (bbase + q0 + ql) * CDIM + ln;
            out[rg]       = x[rg]       + acc0[r] * linv;
            out[rg +  32] = x[rg +  32] + acc1[r] * linv;
            out[rg +  64] = x[rg +  64] + acc2[r] * linv;
            out[rg +  96] = x[rg +  96] + acc3[r] * linv;
            out[rg + 128] = x[rg + 128] + acc4[r] * linv;
            out[rg + 160] = x[rg + 160] + acc5[r] * linv;
            out[rg + 192] = x[rg + 192] + acc6[r] * linv;
            out[rg + 224] = x[rg + 224] + acc7[r] * linv;
        }
    }
}

// ---------------- Kernel 3: combine partials ------------------------------
// out[b,q,:] = x[b,q,:] + (sum_ks O[ks,b,q,:]) / (sum_ks l[ks,b,q]).
// 4096 blocks x 4 waves; one 256-ch row per wave (64 lanes x float4).
__global__ __launch_bounds__(256) void combine_kernel(
    const float* __restrict__ x, const float* __restrict__ Op,
    const float* __restrict__ Lp, float* __restrict__ out, int nks)
{
    const int tid = threadIdx.x, w = tid >> 6, lane = tid & 63;
    const int row = blockIdx.x * 4 + w;          // [0, B*N)
    const int b = row >> 12, q = row & (NPIX - 1);

    float l = 0.f;
    for (int ks = 0; ks < nks; ++ks)
        l += Lp[(ks * BATCH + b) * NPIX + q];
    const float linv = 1.f / l;

    float4 a = {0.f, 0.f, 0.f, 0.f};
    for (int ks = 0; ks < nks; ++ks) {
        const float4 v = *(const float4*)&Op[
            (((long long)(ks * BATCH + b) * NPIX + q)) * CDIM + lane * 4];
        a.x += v.x; a.y += v.y; a.z += v.z; a.w += v.w;
    }
    const long long g = ((long long)b * NPIX + q) * CDIM + lane * 4;
    const float4 xv = *(const float4*)&x[g];
    float4 o;
    o.x = xv.x + a.x * linv;
    o.y = xv.y + a.y * linv;
    o.z = xv.z + a.z * linv;
    o.w = xv.w + a.w * linv;
    *(float4*)&out[g] = o;
}

extern "C" void kernel_launch(void* const* d_in, const int* in_sizes, int n_in,
                              void* d_out, int out_size, void* d_ws, size_t ws_size,
                              hipStream_t stream) {
    const float* x  = (const float*)d_in[0];
    const float* Wf = (const float*)d_in[1];
    const float* bf = (const float*)d_in[2];
    const float* Wg = (const float*)d_in[3];
    const float* bg = (const float*)d_in[4];
    const float* Wh = (const float*)d_in[5];
    const float* bh = (const float*)d_in[6];
    float* out = (float*)d_out;

    ushort* fbf = (ushort*)d_ws;                 // bf16 keys      [B*N,32]
    ushort* gbf = fbf + BATCH * NPIX * CKD;      // bf16 queries   [B*N,32]
    ushort* glo = gbf + BATCH * NPIX * CKD;      // bf16 q-residual[B*N,32]
    ushort* ht  = glo + BATCH * NPIX * CKD;      // bf16 tiled values^T
    ushort* Wt  = ht + BATCH * NPIX * CDIM;      // bf16 [320,256]
    char*   pb  = (char*)(Wt + 320 * 256);       // end of base usage

    const size_t base_used = (size_t)(pb - (char*)d_ws);
    float* Opart = nullptr;
    float* Lpart = nullptr;
    int nks = 1;
    for (int cand = 4; cand >= 3; --cand) {      // prefer 4 (512 blocks, 2/CU)
        size_t oe = (size_t)cand * BATCH * NPIX * CDIM;
        size_t le = (size_t)cand * BATCH * NPIX;
        if (ws_size >= base_used + (oe + le) * sizeof(float)) {
            nks = cand;
            Opart = (float*)pb;
            Lpart = Opart + oe;
            break;
        }
    }

    prep_kernel<<<dim3(18), 256, 0, stream>>>(Wh, Wf, Wg, Wt);
    proj_kernel<<<dim3(512), 256, 0, stream>>>(x, Wt, bf, bg, bh, fbf, gbf, glo, ht);
    attn_kernel<<<dim3(128 * nks), 256, 0, stream>>>(x, fbf, gbf, glo, ht, out,
                                                     Opart, Lpart, nks);
    if (nks > 1)
        combine_kernel<<<dim3(BATCH * NPIX / 4), 256, 0, stream>>>(x, Opart, Lpart, out, nks);
}